// Round 6
// baseline (321.674 us; speedup 1.0000x reference)
//
#include <hip/hip_runtime.h>
#include <hip/hip_bf16.h>

// MarkowitzPortfolioOptimizer. All tensors f32.
// R6: ONE fused kernel, 512 blocks x 256 threads, 8 rows/wave (2 waves/SIMD).
//  - phase 0: stage W to LDS; wave0(tid<32): MLP per row -> mu(global), p(LDS);
//             wave3: redundant per-block power iteration -> step (LDS).
//  - loop: pack y bf16 hi/lo (flat) -> LDS -> B-frags; 24 MFMA (hi/lo split);
//          acc relayout C->flat via swizzled LDS; Newton/Michelot with
//          int-encoded (f,count) 8-lane reductions; momentum. No barriers in loop.

#define B_ROWS 16384
#define NA 64
#define N_FISTA 200
#define N_POWER 128

typedef __attribute__((ext_vector_type(4))) float f32x4;
typedef __attribute__((ext_vector_type(8))) short s16x8;
typedef __attribute__((ext_vector_type(4))) int i32x4;

union V4 {
  i32x4 i;
  s16x8 s;
  f32x4 f;
};

__device__ __forceinline__ unsigned fu(float x) { return __float_as_uint(x); }
__device__ __forceinline__ float uf(unsigned x) { return __uint_as_float(x); }

__device__ __forceinline__ float rdlane(float v, int l) {
  return __int_as_float(__builtin_amdgcn_readlane(__float_as_int(v), l));
}

__device__ __forceinline__ float wave_sum64(float x) {
#pragma unroll
  for (int m = 32; m >= 1; m >>= 1) x += __shfl_xor(x, m, 64);
  return x;
}

__device__ __forceinline__ float matvec64(const float* sig, float y) {
  float g0 = 0.f, g1 = 0.f, g2 = 0.f, g3 = 0.f;
#pragma unroll
  for (int i = 0; i < 64; i += 4) {
    g0 = fmaf(sig[i + 0], rdlane(y, i + 0), g0);
    g1 = fmaf(sig[i + 1], rdlane(y, i + 1), g1);
    g2 = fmaf(sig[i + 2], rdlane(y, i + 2), g2);
    g3 = fmaf(sig[i + 3], rdlane(y, i + 3), g3);
  }
  return (g0 + g1) + (g2 + g3);
}

__global__ __launch_bounds__(256, 2) void fused_kernel(
    const float* __restrict__ x,
    const float* __restrict__ W1, const float* __restrict__ b1,
    const float* __restrict__ W2, const float* __restrict__ b2,
    const float* __restrict__ W3, const float* __restrict__ b3,
    const float* __restrict__ sigma, const float* __restrict__ gamma,
    float* __restrict__ w_out, float* __restrict__ mu_out) {
  __shared__ float sW1[128 * 32];
  __shared__ float sW2[32 * 16];
  __shared__ float sW3[16 * 64];
  __shared__ float sb1[32], sb2[16], sb3[64];
  __shared__ float s_step;
  // per-wave grad/p buffer, XOR-swizzled 16B blocks: logical block b of row r
  // lives at physical block (b ^ r). 8 rows x 64 f32 per wave.
  __shared__ __align__(16) float v_lds[4][8][64];
  // per-wave y buffer: [plane hi/lo][8 rows][64 bf16], blocks (8/row) swizzled b^r
  __shared__ __align__(16) unsigned short y_lds[4][2][8][64];

  const int tid = threadIdx.x;
  const int wv = tid >> 6;
  const int lane = tid & 63;
  const int r = lane & 15;   // C/B-layout column (batch row; rows 8-15 duplicate)
  const int q = lane >> 4;
  const int fr = lane & 7;   // flat: row
  const int fa = lane >> 3;  // flat: asset block (8 assets each)

  // ---- stage MLP weights ----
  for (int i = tid * 4; i < 128 * 32; i += 1024) *(f32x4*)&sW1[i] = *(const f32x4*)&W1[i];
  for (int i = tid; i < 32 * 16; i += 256) sW2[i] = W2[i];
  for (int i = tid * 4; i < 16 * 64; i += 1024) *(f32x4*)&sW3[i] = *(const f32x4*)&W3[i];
  if (tid < 32) sb1[tid] = b1[tid];
  if (tid < 16) sb2[tid] = b2[tid];
  if (tid < 64) sb3[tid] = b3[tid];

  // ---- A-frags (Sigma hi/lo bf16), all waves. A[m=r][k=8q+jj+32s]=sigma[16t+r][k]
  s16x8 a_hi[8], a_lo[8];
#pragma unroll
  for (int t = 0; t < 4; ++t) {
#pragma unroll
    for (int s = 0; s < 2; ++s) {
      const float* sp = sigma + (16 * t + r) * 64 + 32 * s + 8 * q;
      f32x4 A0 = *(const f32x4*)sp;
      f32x4 A1 = *(const f32x4*)(sp + 4);
      float e[8] = {A0.x, A0.y, A0.z, A0.w, A1.x, A1.y, A1.z, A1.w};
      unsigned h[8], lu[8];
#pragma unroll
      for (int k = 0; k < 8; ++k) {
        h[k] = fu(e[k]) & 0xFFFF0000u;
        lu[k] = fu(e[k] - uf(h[k])) + 0x8000u;
      }
      V4 hv, lv;
      hv.i = i32x4{(int)((h[0] >> 16) | h[1]), (int)((h[2] >> 16) | h[3]),
                   (int)((h[4] >> 16) | h[5]), (int)((h[6] >> 16) | h[7])};
      lv.i = i32x4{(int)((lu[0] >> 16) | (lu[1] & 0xFFFF0000u)),
                   (int)((lu[2] >> 16) | (lu[3] & 0xFFFF0000u)),
                   (int)((lu[4] >> 16) | (lu[5] & 0xFFFF0000u)),
                   (int)((lu[6] >> 16) | (lu[7] & 0xFFFF0000u))};
      a_hi[t * 2 + s] = hv.s;
      a_lo[t * 2 + s] = lv.s;
    }
  }

  __syncthreads();

  // ---- phase 0 ----
  if (wv == 3) {
    // redundant per-block power iteration (deterministic -> identical step)
    float sig[64];
#pragma unroll
    for (int i = 0; i < 64; ++i) sig[i] = sigma[i * 64 + lane];
    float v = 0.125f;
    for (int it = 0; it < N_POWER; ++it) {
      v = matvec64(sig, v);
      if ((it & 15) == 15) v *= rsqrtf(wave_sum64(v * v));
    }
    v *= rsqrtf(wave_sum64(v * v));
    float u = matvec64(sig, v);
    float num = wave_sum64(v * u);  // Rayleigh quotient, ||v||=1
    if (lane == 0) s_step = 1.0f / num;
  }
  if (tid < 32) {
    // MLP for this block's 32 rows (thread-per-row; verified R5 code)
    const int row = blockIdx.x * 32 + tid;
    const float gamma_f = gamma[0];
    float h1[32];
#pragma unroll
    for (int j = 0; j < 32; ++j) h1[j] = sb1[j];
    for (int k = 0; k < 128; k += 4) {
      f32x4 xk = *(const f32x4*)&x[row * 128 + k];
#pragma unroll
      for (int j = 0; j < 32; ++j) {
        h1[j] = fmaf(xk.x, sW1[(k + 0) * 32 + j], h1[j]);
        h1[j] = fmaf(xk.y, sW1[(k + 1) * 32 + j], h1[j]);
        h1[j] = fmaf(xk.z, sW1[(k + 2) * 32 + j], h1[j]);
        h1[j] = fmaf(xk.w, sW1[(k + 3) * 32 + j], h1[j]);
      }
    }
#pragma unroll
    for (int j = 0; j < 32; ++j) h1[j] = fmaxf(h1[j], 0.0f);
    float h2[16];
#pragma unroll
    for (int j = 0; j < 16; ++j) h2[j] = sb2[j];
#pragma unroll
    for (int k = 0; k < 32; ++k) {
#pragma unroll
      for (int j = 0; j < 16; ++j) h2[j] = fmaf(h1[k], sW2[k * 16 + j], h2[j]);
    }
#pragma unroll
    for (int j = 0; j < 16; ++j) h2[j] = fmaxf(h2[j], 0.0f);
    const int sw = tid & 7;
    float* vrow = &v_lds[tid >> 3][sw][0];
    for (int b = 0; b < 16; ++b) {
      f32x4 mu4;
#pragma unroll
      for (int j = 0; j < 4; ++j) {
        int o = 4 * b + j;
        float mu = sb3[o];
#pragma unroll
        for (int k = 0; k < 16; ++k) mu = fmaf(h2[k], sW3[k * 64 + o], mu);
        mu4[j] = mu;
      }
      *(f32x4*)&mu_out[row * 64 + 4 * b] = mu4;
      f32x4 p4 = {-gamma_f * mu4.x, -gamma_f * mu4.y, -gamma_f * mu4.z, -gamma_f * mu4.w};
      *(f32x4*)&vrow[((b ^ sw) * 4)] = p4;  // p into swizzled grad buffer
    }
  }

  __syncthreads();

  const float step = s_step;
  const float nstep = -step;

  // pf: C-layout p fragments (lanes r>=8 duplicate row r&7 -> identical cols)
  const int rc = r & 7;
  f32x4 pf[4];
#pragma unroll
  for (int t = 0; t < 4; ++t)
    pf[t] = *(const f32x4*)&v_lds[wv][rc][((4 * t + q) ^ rc) * 4];
  __syncthreads();  // everyone has pf before loop overwrites v_lds

  // LDS pointers
  float* const grow_w = &v_lds[wv][rc][0];                  // C-layout acc writes
  const float* const grow_r = &v_lds[wv][fr][0];            // flat reads
  unsigned short* const yw_h = &y_lds[wv][0][fr][0];        // flat y writes
  unsigned short* const yw_l = &y_lds[wv][1][fr][0];
  const unsigned short* const yr_h = &y_lds[wv][0][rc][0];  // B-frag reads
  const unsigned short* const yr_l = &y_lds[wv][1][rc][0];
  const int b32a = ((lane ^ 32) << 2), b48a = ((lane ^ 48) << 2);

  float y8[8], w8[8];
#pragma unroll
  for (int i = 0; i < 8; ++i) { y8[i] = 1.0f / 64.0f; w8[i] = 1.0f / 64.0f; }
  float t_m = 1.0f, theta = 0.0f;
  int n_prev = 64;

#pragma unroll 1
  for (int it = 0; it < N_FISTA; ++it) {
    // ---- 1. pack y hi/lo (flat layout) -> LDS
    {
      unsigned yb[8], lb[8];
#pragma unroll
      for (int i = 0; i < 8; ++i) {
        yb[i] = fu(y8[i]);
        lb[i] = fu(y8[i] - uf(yb[i] & 0xFFFF0000u)) + 0x8000u;
      }
      i32x4 hi4{(int)__builtin_amdgcn_perm(yb[1], yb[0], 0x07060302u),
                (int)__builtin_amdgcn_perm(yb[3], yb[2], 0x07060302u),
                (int)__builtin_amdgcn_perm(yb[5], yb[4], 0x07060302u),
                (int)__builtin_amdgcn_perm(yb[7], yb[6], 0x07060302u)};
      i32x4 lo4{(int)__builtin_amdgcn_perm(lb[1], lb[0], 0x07060302u),
                (int)__builtin_amdgcn_perm(lb[3], lb[2], 0x07060302u),
                (int)__builtin_amdgcn_perm(lb[5], lb[4], 0x07060302u),
                (int)__builtin_amdgcn_perm(lb[7], lb[6], 0x07060302u)};
      *(i32x4*)&yw_h[(fa ^ fr) * 8] = hi4;
      *(i32x4*)&yw_l[(fa ^ fr) * 8] = lo4;
    }
    __asm__ __volatile__("" ::: "memory");

    // ---- 2. B-frags (cols 8-15 read row rc -> duplicated, discarded later)
    V4 bh0, bh1, bl0, bl1;
    bh0.i = *(const i32x4*)&yr_h[(q ^ rc) * 8];
    bh1.i = *(const i32x4*)&yr_h[((4 + q) ^ rc) * 8];
    bl0.i = *(const i32x4*)&yr_l[(q ^ rc) * 8];
    bl1.i = *(const i32x4*)&yr_l[((4 + q) ^ rc) * 8];
    __asm__ __volatile__("" ::: "memory");

    // ---- 3. acc = Sigma@Y^T + P (hi*hi + lo*hi + hi*lo); write C->flat LDS
#pragma unroll
    for (int t = 0; t < 4; ++t) {
      f32x4 acc = pf[t];
      acc = __builtin_amdgcn_mfma_f32_16x16x32_bf16(a_hi[t * 2 + 0], bh0.s, acc, 0, 0, 0);
      acc = __builtin_amdgcn_mfma_f32_16x16x32_bf16(a_hi[t * 2 + 1], bh1.s, acc, 0, 0, 0);
      acc = __builtin_amdgcn_mfma_f32_16x16x32_bf16(a_lo[t * 2 + 0], bh0.s, acc, 0, 0, 0);
      acc = __builtin_amdgcn_mfma_f32_16x16x32_bf16(a_lo[t * 2 + 1], bh1.s, acc, 0, 0, 0);
      acc = __builtin_amdgcn_mfma_f32_16x16x32_bf16(a_hi[t * 2 + 0], bl0.s, acc, 0, 0, 0);
      acc = __builtin_amdgcn_mfma_f32_16x16x32_bf16(a_hi[t * 2 + 1], bl1.s, acc, 0, 0, 0);
      // lanes r>=8 write identical duplicates (benign same-value race)
      *(f32x4*)&grow_w[((4 * t + q) ^ rc) * 4] = acc;
    }
    __asm__ __volatile__("" ::: "memory");

    // ---- 4. flat read + v = y - step*grad
    f32x4 g0 = *(const f32x4*)&grow_r[((2 * fa + 0) ^ fr) * 4];
    f32x4 g1 = *(const f32x4*)&grow_r[((2 * fa + 1) ^ fr) * 4];
    __asm__ __volatile__("" ::: "memory");
    float vv[8];
    vv[0] = fmaf(nstep, g0.x, y8[0]); vv[1] = fmaf(nstep, g0.y, y8[1]);
    vv[2] = fmaf(nstep, g0.z, y8[2]); vv[3] = fmaf(nstep, g0.w, y8[3]);
    vv[4] = fmaf(nstep, g1.x, y8[4]); vv[5] = fmaf(nstep, g1.y, y8[5]);
    vv[6] = fmaf(nstep, g1.z, y8[6]); vv[7] = fmaf(nstep, g1.w, y8[7]);

    // ---- 5. Newton/Michelot, warm theta. (f, inactive-count) int-encoded:
    //         bits 0-23 = f*2^14 (f_sum < 512), bits 24+ = count (<=64).
#pragma unroll 1
    for (int mm = 0; mm < 16; ++mm) {
      float f = 0.0f;
      int sc = 0;
#pragma unroll
      for (int i = 0; i < 8; ++i) {
        float d = vv[i] - theta;
        f += fmaxf(d, 0.0f);
        sc += (__float_as_int(d) >> 31);  // -1 if d<0
      }
      int Fi = (int)(f * 16384.0f) - (sc << 24);
      Fi += __builtin_amdgcn_ds_swizzle(Fi, 0x201F);  // + lane^8
      int s16 = __builtin_amdgcn_ds_swizzle(Fi, 0x401F);
      int s32 = __builtin_amdgcn_ds_bpermute(b32a, Fi);
      int s48 = __builtin_amdgcn_ds_bpermute(b48a, Fi);
      Fi = (Fi + s16) + (s32 + s48);
      int n = 64 - (int)((unsigned)Fi >> 24);
      float fs = (float)(Fi & 0xFFFFFF) * (1.0f / 16384.0f);
      int ng = n > 1 ? n : 1;
      theta += (fs - 1.0f) * __builtin_amdgcn_rcpf((float)ng);
      bool changed = (n != n_prev);
      n_prev = n;
      if (__ballot(changed) == 0ull) break;
    }

    // ---- 6. project + momentum
    float tn = 0.5f * (1.0f + sqrtf(fmaf(4.0f * t_m, t_m, 1.0f)));
    float c = (t_m - 1.0f) * __builtin_amdgcn_rcpf(tn);
#pragma unroll
    for (int i = 0; i < 8; ++i) {
      float wn = fmaxf(vv[i] - theta, 0.0f);
      y8[i] = fmaf(c, wn - w8[i], wn);
      w8[i] = wn;
    }
    t_m = tn;
  }

  // ---- store w (flat layout, coalesced 2KB/wave)
  const int grow = blockIdx.x * 32 + wv * 8 + fr;
  f32x4 s0{w8[0], w8[1], w8[2], w8[3]};
  f32x4 s1{w8[4], w8[5], w8[6], w8[7]};
  *(f32x4*)&w_out[grow * 64 + 8 * fa] = s0;
  *(f32x4*)&w_out[grow * 64 + 8 * fa + 4] = s1;
}

extern "C" void kernel_launch(void* const* d_in, const int* in_sizes, int n_in,
                              void* d_out, int out_size, void* d_ws, size_t ws_size,
                              hipStream_t stream) {
  const float* x = (const float*)d_in[0];
  const float* W1 = (const float*)d_in[1];
  const float* b1 = (const float*)d_in[2];
  const float* W2 = (const float*)d_in[3];
  const float* b2 = (const float*)d_in[4];
  const float* W3 = (const float*)d_in[5];
  const float* b3 = (const float*)d_in[6];
  const float* sigma = (const float*)d_in[7];
  const float* gamma = (const float*)d_in[8];

  float* out = (float*)d_out;
  float* w_out = out;                         // [B, 64] weights
  float* mu_out = out + (size_t)B_ROWS * NA;  // [B, 64] mu

  fused_kernel<<<B_ROWS / 32, 256, 0, stream>>>(x, W1, b1, W2, b2, W3, b3,
                                                sigma, gamma, w_out, mu_out);
}

// Round 8
// 291.342 us; speedup vs baseline: 1.1041x; 1.1041x over previous
//
#include <hip/hip_runtime.h>
#include <hip/hip_bf16.h>

// MarkowitzPortfolioOptimizer. All tensors f32.
// R8 = R7 with compile fix (DPP ctrl as template constant).
// G^T = Y @ Sigma orientation: batch rows on the MFMA M dimension ->
// C-layout puts each batch row in one 16-lane DPP row (4 regs). Projection
// (warm-started Michelot/Newton) is pure-VALU via row_ror DPP reductions,
// packed-int count channel. Only LDS in the loop: y C->A transpose
// (16 b32 writes @ stride-68 rows = 2-way free; 4 b128 reads conflict-free).

#define B_ROWS 16384
#define NA 64
#define N_FISTA 200
#define N_POWER 96
#define YSTRIDE 68  // floats; 68&31=4 -> write banks 2-way, b128 reads minimal

typedef __attribute__((ext_vector_type(4))) float f32x4;
typedef __attribute__((ext_vector_type(8))) short s16x8;
typedef __attribute__((ext_vector_type(4))) int i32x4;

union V4 {
  i32x4 i;
  s16x8 s;
  f32x4 f;
};

__device__ __forceinline__ unsigned fu(float x) { return __float_as_uint(x); }
__device__ __forceinline__ float uf(unsigned x) { return __uint_as_float(x); }

__device__ __forceinline__ float rdlane(float v, int l) {
  return __int_as_float(__builtin_amdgcn_readlane(__float_as_int(v), l));
}

__device__ __forceinline__ float wave_sum64(float x) {
#pragma unroll
  for (int m = 32; m >= 1; m >>= 1) x += __shfl_xor(x, m, 64);
  return x;
}

__device__ __forceinline__ float matvec64(const float* sig, float y) {
  float g0 = 0.f, g1 = 0.f, g2 = 0.f, g3 = 0.f;
#pragma unroll
  for (int i = 0; i < 64; i += 4) {
    g0 = fmaf(sig[i + 0], rdlane(y, i + 0), g0);
    g1 = fmaf(sig[i + 1], rdlane(y, i + 1), g1);
    g2 = fmaf(sig[i + 2], rdlane(y, i + 2), g2);
    g3 = fmaf(sig[i + 3], rdlane(y, i + 3), g3);
  }
  return (g0 + g1) + (g2 + g3);
}

// DPP helpers — ctrl MUST be a compile-time constant => template parameter.
template <int CTRL>
__device__ __forceinline__ float dppf(float v) {
  return __int_as_float(
      __builtin_amdgcn_update_dpp(0, __float_as_int(v), CTRL, 0xF, 0xF, false));
}
template <int CTRL>
__device__ __forceinline__ int dppi(int v) {
  return __builtin_amdgcn_update_dpp(0, v, CTRL, 0xF, 0xF, false);
}

// one row_ror reduction step over the 4 f-channels + count channel
template <int ST>
__device__ __forceinline__ void red_step(float& f0, float& f1, float& f2,
                                         float& f3, int& enc) {
  f0 += dppf<0x120 + ST>(f0);
  f1 += dppf<0x120 + ST>(f1);
  f2 += dppf<0x120 + ST>(f2);
  f3 += dppf<0x120 + ST>(f3);
  enc += dppi<0x120 + ST>(enc);
}

// pack 8 f32 -> bf16 hi (truncate) and lo (rne residual) fragments
__device__ __forceinline__ void pack_hilo(const f32x4& e0, const f32x4& e1,
                                          s16x8& hi, s16x8& lo) {
  unsigned a0 = fu(e0.x), a1 = fu(e0.y), a2 = fu(e0.z), a3 = fu(e0.w);
  unsigned a4 = fu(e1.x), a5 = fu(e1.y), a6 = fu(e1.z), a7 = fu(e1.w);
  V4 hv, lv;
  hv.i = i32x4{(int)__builtin_amdgcn_perm(a1, a0, 0x07060302u),
               (int)__builtin_amdgcn_perm(a3, a2, 0x07060302u),
               (int)__builtin_amdgcn_perm(a5, a4, 0x07060302u),
               (int)__builtin_amdgcn_perm(a7, a6, 0x07060302u)};
  unsigned l0 = fu(uf(a0) - uf(a0 & 0xFFFF0000u)) + 0x8000u;
  unsigned l1 = fu(uf(a1) - uf(a1 & 0xFFFF0000u)) + 0x8000u;
  unsigned l2 = fu(uf(a2) - uf(a2 & 0xFFFF0000u)) + 0x8000u;
  unsigned l3 = fu(uf(a3) - uf(a3 & 0xFFFF0000u)) + 0x8000u;
  unsigned l4 = fu(uf(a4) - uf(a4 & 0xFFFF0000u)) + 0x8000u;
  unsigned l5 = fu(uf(a5) - uf(a5 & 0xFFFF0000u)) + 0x8000u;
  unsigned l6 = fu(uf(a6) - uf(a6 & 0xFFFF0000u)) + 0x8000u;
  unsigned l7 = fu(uf(a7) - uf(a7 & 0xFFFF0000u)) + 0x8000u;
  lv.i = i32x4{(int)__builtin_amdgcn_perm(l1, l0, 0x07060302u),
               (int)__builtin_amdgcn_perm(l3, l2, 0x07060302u),
               (int)__builtin_amdgcn_perm(l5, l4, 0x07060302u),
               (int)__builtin_amdgcn_perm(l7, l6, 0x07060302u)};
  hi = hv.s;
  lo = lv.s;
}

__global__ __launch_bounds__(256, 1) void fused_kernel(
    const float* __restrict__ x,
    const float* __restrict__ W1, const float* __restrict__ b1,
    const float* __restrict__ W2, const float* __restrict__ b2,
    const float* __restrict__ W3, const float* __restrict__ b3,
    const float* __restrict__ sigma, const float* __restrict__ gamma,
    float* __restrict__ w_out, float* __restrict__ mu_out) {
  __shared__ float sW1[128 * 32];
  __shared__ float sW2[32 * 16];
  __shared__ float sW3[16 * 64];
  __shared__ float sb1[32], sb2[16], sb3[64];
  __shared__ float s_step;
  __shared__ float p_lds[64 * 64];                    // p for this block's 64 rows
  __shared__ __align__(16) float y_lds[4][16 * YSTRIDE];  // per-wave y, stride-68

  const int tid = threadIdx.x;
  const int wv = tid >> 6;
  const int lane = tid & 63;
  const int r16 = lane & 15;
  const int q = lane >> 4;
  const int rowbase = blockIdx.x * 64 + wv * 16;

  // ---- stage MLP weights ----
  for (int i = tid * 4; i < 128 * 32; i += 1024) *(f32x4*)&sW1[i] = *(const f32x4*)&W1[i];
  for (int i = tid; i < 32 * 16; i += 256) sW2[i] = W2[i];
  for (int i = tid * 4; i < 16 * 64; i += 1024) *(f32x4*)&sW3[i] = *(const f32x4*)&W3[i];
  if (tid < 32) sb1[tid] = b1[tid];
  if (tid < 16) sb2[tid] = b2[tid];
  if (tid < 64) sb3[tid] = b3[tid];

  // ---- B-frags: Sigma (wave-uniform). B[k=8q+j+32s][n=16t+r16] = sigma[16t+r16][k]
  s16x8 b_hi[8], b_lo[8];  // [t*2+s]
#pragma unroll
  for (int t = 0; t < 4; ++t) {
#pragma unroll
    for (int s = 0; s < 2; ++s) {
      const float* sp = sigma + (16 * t + r16) * 64 + 32 * s + 8 * q;
      pack_hilo(*(const f32x4*)sp, *(const f32x4*)(sp + 4), b_hi[t * 2 + s],
                b_lo[t * 2 + s]);
    }
  }

  __syncthreads();

  // ---- phase 0: wave3 = power iteration; wave0 = MLP (64 rows) ----
  if (wv == 3) {
    float sig[64];
#pragma unroll
    for (int i = 0; i < 64; ++i) sig[i] = sigma[i * 64 + lane];
    float v = 0.125f;
    for (int it = 0; it < N_POWER; ++it) {
      v = matvec64(sig, v);
      if ((it & 15) == 15) v *= rsqrtf(wave_sum64(v * v));
    }
    v *= rsqrtf(wave_sum64(v * v));
    float u = matvec64(sig, v);
    float num = wave_sum64(v * u);
    if (lane == 0) s_step = 1.0f / num;
  }
  if (tid < 64) {
    const int row = blockIdx.x * 64 + tid;
    const float gamma_f = gamma[0];
    float h1[32];
#pragma unroll
    for (int j = 0; j < 32; ++j) h1[j] = sb1[j];
    for (int k = 0; k < 128; k += 4) {
      f32x4 xk = *(const f32x4*)&x[row * 128 + k];
#pragma unroll
      for (int j = 0; j < 32; ++j) {
        h1[j] = fmaf(xk.x, sW1[(k + 0) * 32 + j], h1[j]);
        h1[j] = fmaf(xk.y, sW1[(k + 1) * 32 + j], h1[j]);
        h1[j] = fmaf(xk.z, sW1[(k + 2) * 32 + j], h1[j]);
        h1[j] = fmaf(xk.w, sW1[(k + 3) * 32 + j], h1[j]);
      }
    }
#pragma unroll
    for (int j = 0; j < 32; ++j) h1[j] = fmaxf(h1[j], 0.0f);
    float h2[16];
#pragma unroll
    for (int j = 0; j < 16; ++j) h2[j] = sb2[j];
#pragma unroll
    for (int k = 0; k < 32; ++k) {
#pragma unroll
      for (int j = 0; j < 16; ++j) h2[j] = fmaf(h1[k], sW2[k * 16 + j], h2[j]);
    }
#pragma unroll
    for (int j = 0; j < 16; ++j) h2[j] = fmaxf(h2[j], 0.0f);
    for (int b = 0; b < 16; ++b) {
      f32x4 mu4;
#pragma unroll
      for (int j = 0; j < 4; ++j) {
        int o = 4 * b + j;
        float mu = sb3[o];
#pragma unroll
        for (int k = 0; k < 16; ++k) mu = fmaf(h2[k], sW3[k * 64 + o], mu);
        mu4[j] = mu;
      }
      *(f32x4*)&mu_out[row * 64 + 4 * b] = mu4;
      f32x4 p4 = {-gamma_f * mu4.x, -gamma_f * mu4.y, -gamma_f * mu4.z, -gamma_f * mu4.w};
      *(f32x4*)&p_lds[tid * 64 + 4 * b] = p4;
    }
  }

  __syncthreads();

  const float step = s_step;
  const float nstep = -step;

  // ---- P^T in C-layout: pf[t*4+i] = p[rowbase + 4q + i][16t + r16]
  float pf[16];
#pragma unroll
  for (int t = 0; t < 4; ++t)
#pragma unroll
    for (int i = 0; i < 4; ++i)
      pf[t * 4 + i] = p_lds[(wv * 16 + 4 * q + i) * 64 + 16 * t + r16];

  // ---- y LDS pointers (per-wave private) ----
  float* const ywr = &y_lds[wv][4 * q * YSTRIDE + r16];  // + i*YSTRIDE + 16t imm
  const float* const yrd = &y_lds[wv][r16 * YSTRIDE + 8 * q];  // + {0,4,32,36} imm

  // ---- state (C-layout): yc/wc[t*4+i] ----
  float yc[16], wc[16];
#pragma unroll
  for (int i = 0; i < 16; ++i) { yc[i] = 1.0f / 64.0f; wc[i] = 1.0f / 64.0f; }
  float th0 = 0.f, th1 = 0.f, th2 = 0.f, th3 = 0.f;  // theta per reg (row 4q+i)
  int enc_prev = 0x40404040;                          // n=64 per field
  float t_m = 1.0f;

  // initial y -> LDS
#pragma unroll
  for (int t = 0; t < 4; ++t)
#pragma unroll
    for (int i = 0; i < 4; ++i) ywr[i * YSTRIDE + 16 * t] = yc[t * 4 + i];
  __asm__ __volatile__("" ::: "memory");

#pragma unroll 1
  for (int it = 0; it < N_FISTA; ++it) {
    // ---- 1. A-frags from LDS (row r16, assets 8q..+7, +32): pack bf16 hi/lo
    f32x4 r0 = *(const f32x4*)(yrd);
    f32x4 r1 = *(const f32x4*)(yrd + 4);
    f32x4 r2 = *(const f32x4*)(yrd + 32);
    f32x4 r3 = *(const f32x4*)(yrd + 36);
    __asm__ __volatile__("" ::: "memory");
    s16x8 a_h0, a_l0, a_h1, a_l1;
    pack_hilo(r0, r1, a_h0, a_l0);
    pack_hilo(r2, r3, a_h1, a_l1);

    // ---- 2. G^T tiles + v = y - step*g (C-layout)
    float vc[16];
#pragma unroll
    for (int t = 0; t < 4; ++t) {
      f32x4 acc{pf[t * 4 + 0], pf[t * 4 + 1], pf[t * 4 + 2], pf[t * 4 + 3]};
      acc = __builtin_amdgcn_mfma_f32_16x16x32_bf16(a_h0, b_hi[t * 2 + 0], acc, 0, 0, 0);
      acc = __builtin_amdgcn_mfma_f32_16x16x32_bf16(a_h1, b_hi[t * 2 + 1], acc, 0, 0, 0);
      acc = __builtin_amdgcn_mfma_f32_16x16x32_bf16(a_l0, b_hi[t * 2 + 0], acc, 0, 0, 0);
      acc = __builtin_amdgcn_mfma_f32_16x16x32_bf16(a_l1, b_hi[t * 2 + 1], acc, 0, 0, 0);
      acc = __builtin_amdgcn_mfma_f32_16x16x32_bf16(a_h0, b_lo[t * 2 + 0], acc, 0, 0, 0);
      acc = __builtin_amdgcn_mfma_f32_16x16x32_bf16(a_h1, b_lo[t * 2 + 1], acc, 0, 0, 0);
      vc[t * 4 + 0] = fmaf(nstep, acc.x, yc[t * 4 + 0]);
      vc[t * 4 + 1] = fmaf(nstep, acc.y, yc[t * 4 + 1]);
      vc[t * 4 + 2] = fmaf(nstep, acc.z, yc[t * 4 + 2]);
      vc[t * 4 + 3] = fmaf(nstep, acc.w, yc[t * 4 + 3]);
    }

    // ---- 3. Newton/Michelot, pure VALU (row_ror reductions within DPP rows)
#pragma unroll 1
    for (int mm = 0; mm < 16; ++mm) {
      float f0 = 0.f, f1 = 0.f, f2 = 0.f, f3 = 0.f;
      int enc = 0x04040404;  // +4 offset per field; field i accumulates n_i
#pragma unroll
      for (int t = 0; t < 4; ++t) {
        float d0 = vc[t * 4 + 0] - th0;
        float d1 = vc[t * 4 + 1] - th1;
        float d2 = vc[t * 4 + 2] - th2;
        float d3 = vc[t * 4 + 3] - th3;
        f0 += fmaxf(d0, 0.f); f1 += fmaxf(d1, 0.f);
        f2 += fmaxf(d2, 0.f); f3 += fmaxf(d3, 0.f);
        enc += (__float_as_int(d0) >> 31);
        enc += (__float_as_int(d1) >> 31) << 8;
        enc += (__float_as_int(d2) >> 31) << 16;
        enc += (__float_as_int(d3) >> 31) << 24;
      }
      // 16-lane reductions (rotations within DPP row = lanes 16q..16q+15)
      red_step<1>(f0, f1, f2, f3, enc);
      red_step<2>(f0, f1, f2, f3, enc);
      red_step<4>(f0, f1, f2, f3, enc);
      red_step<8>(f0, f1, f2, f3, enc);
      int n0 = enc & 0xFF, n1 = (enc >> 8) & 0xFF, n2 = (enc >> 16) & 0xFF,
          n3 = (enc >> 24) & 0xFF;
      th0 += (f0 - 1.f) * __builtin_amdgcn_rcpf((float)(n0 > 1 ? n0 : 1));
      th1 += (f1 - 1.f) * __builtin_amdgcn_rcpf((float)(n1 > 1 ? n1 : 1));
      th2 += (f2 - 1.f) * __builtin_amdgcn_rcpf((float)(n2 > 1 ? n2 : 1));
      th3 += (f3 - 1.f) * __builtin_amdgcn_rcpf((float)(n3 > 1 ? n3 : 1));
      bool changed = (enc != enc_prev);
      enc_prev = enc;
      if (__ballot(changed) == 0ull) break;
    }

    // ---- 4. project + momentum + y->LDS
    float tn = 0.5f * (1.0f + sqrtf(fmaf(4.0f * t_m, t_m, 1.0f)));
    float c = (t_m - 1.0f) * __builtin_amdgcn_rcpf(tn);
#pragma unroll
    for (int t = 0; t < 4; ++t) {
      float wn0 = fmaxf(vc[t * 4 + 0] - th0, 0.f);
      float wn1 = fmaxf(vc[t * 4 + 1] - th1, 0.f);
      float wn2 = fmaxf(vc[t * 4 + 2] - th2, 0.f);
      float wn3 = fmaxf(vc[t * 4 + 3] - th3, 0.f);
      yc[t * 4 + 0] = fmaf(c, wn0 - wc[t * 4 + 0], wn0);
      yc[t * 4 + 1] = fmaf(c, wn1 - wc[t * 4 + 1], wn1);
      yc[t * 4 + 2] = fmaf(c, wn2 - wc[t * 4 + 2], wn2);
      yc[t * 4 + 3] = fmaf(c, wn3 - wc[t * 4 + 3], wn3);
      wc[t * 4 + 0] = wn0; wc[t * 4 + 1] = wn1;
      wc[t * 4 + 2] = wn2; wc[t * 4 + 3] = wn3;
      ywr[0 * YSTRIDE + 16 * t] = yc[t * 4 + 0];
      ywr[1 * YSTRIDE + 16 * t] = yc[t * 4 + 1];
      ywr[2 * YSTRIDE + 16 * t] = yc[t * 4 + 2];
      ywr[3 * YSTRIDE + 16 * t] = yc[t * 4 + 3];
    }
    t_m = tn;
    __asm__ __volatile__("" ::: "memory");
  }

  // ---- store w (C-layout scatter, one-time)
#pragma unroll
  for (int t = 0; t < 4; ++t)
#pragma unroll
    for (int i = 0; i < 4; ++i)
      w_out[(rowbase + 4 * q + i) * 64 + 16 * t + r16] = wc[t * 4 + i];
}

extern "C" void kernel_launch(void* const* d_in, const int* in_sizes, int n_in,
                              void* d_out, int out_size, void* d_ws, size_t ws_size,
                              hipStream_t stream) {
  const float* x = (const float*)d_in[0];
  const float* W1 = (const float*)d_in[1];
  const float* b1 = (const float*)d_in[2];
  const float* W2 = (const float*)d_in[3];
  const float* b2 = (const float*)d_in[4];
  const float* W3 = (const float*)d_in[5];
  const float* b3 = (const float*)d_in[6];
  const float* sigma = (const float*)d_in[7];
  const float* gamma = (const float*)d_in[8];

  float* out = (float*)d_out;
  float* w_out = out;                         // [B, 64] weights
  float* mu_out = out + (size_t)B_ROWS * NA;  // [B, 64] mu

  fused_kernel<<<B_ROWS / 64, 256, 0, stream>>>(x, W1, b1, W2, b2, W3, b3,
                                                sigma, gamma, w_out, mu_out);
}